// Round 4
// baseline (75.185 us; speedup 1.0000x reference)
//
#include <hip/hip_runtime.h>

// YOLO-style loss: pred/target (N, 7, 7, 30) f32 -> 5 scalar losses.
// HBM-streaming reduction, software-pipelined: one wave per block, two
// 15,360 B LDS buffers, global_load_lds direct HBM->LDS, counted
// s_waitcnt vmcnt(15) so the next tile's 15 loads stay in flight across
// the compute phase (never drain to 0 in steady state). 5 blocks/CU.
// No barriers (single wave, private LDS). No atomics: partials -> d_ws.

#define S_GRID 7
#define D_CH   30
#define CPT    64                   // cells per tile (= lanes)
#define T_F4   (CPT * D_CH / 4)     // 480 float4 per tensor per tile
#define BUF_F4 (2 * T_F4)           // 960 float4 per buffer (15,360 B)
#define THREADS 64
#define GRID_BLOCKS 1280            // 5 blocks/CU * 256 CU (LDS-capped)

typedef __attribute__((address_space(3))) void       lds_void;
typedef const __attribute__((address_space(1))) void glb_void;

__device__ __forceinline__ void gload_lds16(const float4* g, float4* l) {
    __builtin_amdgcn_global_load_lds((glb_void*)g, (lds_void*)l, 16, 0, 0);
}

// Issue 15 direct-to-LDS wave loads covering pred+tgt records of one tile.
// LDS dest base wave-uniform per j (HW writes lane*16B); global src per-lane.
__device__ __forceinline__ void stage_tile(const float* __restrict__ pred,
                                           const float* __restrict__ tgt,
                                           long long cell0, float4* buf, int lane) {
    const float4* gp4 = reinterpret_cast<const float4*>(pred + cell0 * D_CH);
    const float4* gt4 = reinterpret_cast<const float4*>(tgt  + cell0 * D_CH);
    #pragma unroll
    for (int j = 0; j < 15; ++j) {
        const int k = j * 64 + lane;
        const float4* src = (k < T_F4) ? (gp4 + k) : (gt4 + (k - T_F4));
        gload_lds16(src, &buf[j * 64]);
    }
}

// Per-cell loss terms; P/T point at one 30-float record each (LDS or global).
__device__ __forceinline__ void cell_loss(const float* P, const float* T,
    float& lxy, float& lwh, float& lobj, float& lnoobj, float& lcls)
{
    const float cellw = 1.0f / (float)S_GRID;

    const float t4 = T[4];
    const float obj   = (t4 == 1.0f) ? 1.0f : 0.0f;
    const float noobj = (t4 == 0.0f) ? 1.0f : 0.0f;

    // target box 0 in ltrb
    const float tlx = T[0] * cellw - T[2] * 0.5f;
    const float tly = T[1] * cellw - T[3] * 0.5f;
    const float trx = T[0] * cellw + T[2] * 0.5f;
    const float tby = T[1] * cellw + T[3] * 0.5f;
    const float area_t = (trx - tlx) * (tby - tly);

    float iou0 = 0.f, iou1 = 0.f;
    #pragma unroll
    for (int b = 0; b < 2; ++b) {
        const float* Pb = P + b * 5;
        const float plx = Pb[0] * cellw - Pb[2] * 0.5f;
        const float ply = Pb[1] * cellw - Pb[3] * 0.5f;
        const float prx = Pb[0] * cellw + Pb[2] * 0.5f;
        const float pby = Pb[1] * cellw + Pb[3] * 0.5f;
        const float ltx = fmaxf(plx, tlx);
        const float lty = fmaxf(ply, tly);
        const float rbx = fminf(prx, trx);
        const float rby = fminf(pby, tby);
        const float wx = fmaxf(rbx - ltx, 0.0f);
        const float wy = fmaxf(rby - lty, 0.0f);
        const float inter = wx * wy;
        const float area_p = (prx - plx) * (pby - ply);
        const float v = inter / (area_p + area_t - inter);
        if (b == 0) iou0 = v; else iou1 = v;
    }

    // argmax first-occurrence tie-break: idx 1 only if strictly greater
    const int bi = (iou1 > iou0) ? 1 : 0;
    const float riou = fmaxf(iou0, iou1);

    const float* Pb = P + bi * 5;
    const float* Tb = T + bi * 5;
    const float dx = Tb[0] - Pb[0];
    const float dy = Tb[1] - Pb[1];
    lxy += obj * (dx * dx + dy * dy);

    const float dw = sqrtf(Tb[2]) - sqrtf(Pb[2]);
    const float dh = sqrtf(Tb[3]) - sqrtf(Pb[3]);
    lwh += obj * (dw * dw + dh * dh);

    const float dc = riou - Pb[4];
    lobj += obj * (dc * dc);

    const float d4 = T[4] - P[4];
    const float d9 = T[9] - P[9];
    lnoobj += noobj * (d4 * d4 + d9 * d9);

    float cs = 0.f;
    #pragma unroll
    for (int c = 10; c < 30; ++c) {
        const float d = T[c] - P[c];
        cs += d * d;
    }
    lcls += obj * cs;
}

__global__ __launch_bounds__(THREADS) void yolo_loss_partial(
    const float* __restrict__ pred, const float* __restrict__ tgt,
    float* __restrict__ ws, int nFullTiles, long long totalCells)
{
    __shared__ float4 stage[2 * BUF_F4];   // double buffer, 30,720 B
    float4* bufA = stage;
    float4* bufB = stage + BUF_F4;

    const int lane = threadIdx.x;          // single wave
    float lxy = 0.f, lwh = 0.f, lobj = 0.f, lnoobj = 0.f, lcls = 0.f;

    long long tile = blockIdx.x;
    int cur = 0;

    // prologue: fill buffer 0
    if (tile < nFullTiles)
        stage_tile(pred, tgt, tile * CPT, bufA, lane);

    for (; tile < nFullTiles; tile += gridDim.x) {
        const long long nxt = tile + gridDim.x;
        float4* bc = cur ? bufB : bufA;
        float4* bn = cur ? bufA : bufB;

        if (nxt < nFullTiles) {
            stage_tile(pred, tgt, nxt * CPT, bn, lane);   // issue next 15 first
            asm volatile("s_waitcnt vmcnt(15)" ::: "memory");  // current tile done
        } else {
            asm volatile("s_waitcnt vmcnt(0)" ::: "memory");   // drain at tail
        }
        __builtin_amdgcn_sched_barrier(0);   // no LDS-read hoisting above wait

        const float* sp = reinterpret_cast<const float*>(bc);
        const float* st = sp + T_F4 * 4;
        cell_loss(sp + lane * D_CH, st + lane * D_CH,
                  lxy, lwh, lobj, lnoobj, lcls);
        cur ^= 1;
    }

    // remainder cells (none for this shape; direct-from-global, block 0 only)
    const long long remStart = (long long)nFullTiles * CPT;
    if (blockIdx.x == 0 && remStart + lane < totalCells) {
        cell_loss(pred + (remStart + lane) * D_CH, tgt + (remStart + lane) * D_CH,
                  lxy, lwh, lobj, lnoobj, lcls);
    }

    // single-wave shuffle reduction; lane 0 writes 5 partials
    #pragma unroll
    for (int off = 32; off > 0; off >>= 1) {
        lxy    += __shfl_down(lxy, off);
        lwh    += __shfl_down(lwh, off);
        lobj   += __shfl_down(lobj, off);
        lnoobj += __shfl_down(lnoobj, off);
        lcls   += __shfl_down(lcls, off);
    }
    if (lane == 0) {
        float* p = ws + (long long)blockIdx.x * 5;
        p[0] = lxy; p[1] = lwh; p[2] = lobj; p[3] = lnoobj; p[4] = lcls;
    }
}

__global__ __launch_bounds__(256) void yolo_loss_reduce(
    const float* __restrict__ ws, float* __restrict__ out,
    int nParts, float inv_n)
{
    __shared__ float red[4][5];
    const int tid = threadIdx.x;
    float s0 = 0.f, s1 = 0.f, s2 = 0.f, s3 = 0.f, s4 = 0.f;
    for (int b = tid; b < nParts; b += 256) {
        const float* p = ws + (long long)b * 5;
        s0 += p[0]; s1 += p[1]; s2 += p[2]; s3 += p[3]; s4 += p[4];
    }
    #pragma unroll
    for (int off = 32; off > 0; off >>= 1) {
        s0 += __shfl_down(s0, off);
        s1 += __shfl_down(s1, off);
        s2 += __shfl_down(s2, off);
        s3 += __shfl_down(s3, off);
        s4 += __shfl_down(s4, off);
    }
    const int wave = tid >> 6;
    const int lane = tid & 63;
    if (lane == 0) {
        red[wave][0] = s0; red[wave][1] = s1; red[wave][2] = s2;
        red[wave][3] = s3; red[wave][4] = s4;
    }
    __syncthreads();
    if (tid < 5) {
        float v = 0.f;
        #pragma unroll
        for (int w = 0; w < 4; ++w) v += red[w][tid];
        out[tid] = v * inv_n;
    }
}

extern "C" void kernel_launch(void* const* d_in, const int* in_sizes, int n_in,
                              void* d_out, int out_size, void* d_ws, size_t ws_size,
                              hipStream_t stream) {
    const float* pred = (const float*)d_in[0];
    const float* tgt  = (const float*)d_in[1];
    float* out = (float*)d_out;
    float* ws  = (float*)d_ws;

    const long long totalFloats = (long long)in_sizes[0];
    const long long totalCells = totalFloats / D_CH;            // N*S*S
    const long long n = totalCells / (S_GRID * S_GRID);         // N
    const float inv_n = 1.0f / (float)n;

    const int nFullTiles = (int)(totalCells / CPT);
    int blocks = (nFullTiles < GRID_BLOCKS) ? nFullTiles : GRID_BLOCKS;
    if (blocks < 1) blocks = 1;   // remainder-only degenerate case

    yolo_loss_partial<<<blocks, THREADS, 0, stream>>>(pred, tgt, ws, nFullTiles, totalCells);
    yolo_loss_reduce<<<1, 256, 0, stream>>>(ws, out, blocks, inv_n);
}